// Round 1
// baseline (120.830 us; speedup 1.0000x reference)
//
#include <hip/hip_runtime.h>

typedef float v2f __attribute__((ext_vector_type(2)));

// ---- problem ----
// x:[4,16,8,64,64] f32, w_q/w_k/w_v:[64,8] f32, w_p:[2] f32
// out:[4,16,64,64,64] f32
// Attention batch B = bb*64 + o: q-side channel i (all 16) row o;
// k/v-side channel o>>2, w_k/w_v rows (o&3)*16+j; uk += 2*pe; scale 0.125
// folded into w_q (plus log2e when exp2 available); residual = mean over m;
// single-pass softmax (|logit| << 88): out = (sum_j e_j*uv_j)/(sum_j e_j).
//
// R11: LDS-traffic halving restructure. Block = (bb, o, tile-QUAD): 4 tiles,
// 4 i per thread (was 2 tiles / 2 i). Every stage-3 s_uk/s_uv b128 read now
// feeds 4 accumulators; stage-2 threads own 2 j x 2 tiles sharing one s_xk
// read set; wk/wv rows come straight from global (L1, broadcast) instead of
// LDS. Stage-1 staging vectorized to float4. exp -> v_exp_f32 via log2e
// folded into wq. LDS = 40960 B exactly -> 4 blocks/CU.

#if __has_builtin(__builtin_amdgcn_exp2f)
  #define EXP_FN(x) __builtin_amdgcn_exp2f(x)
  #define QSCALE 0.18033688011112043f   // 0.125 * log2(e)
#else
  #define EXP_FN(x) __expf(x)
  #define QSCALE 0.125f
#endif

__global__ __launch_bounds__(256, 4) void adapt_attn(
    const float* __restrict__ x,  const float* __restrict__ wq,
    const float* __restrict__ wk, const float* __restrict__ wv,
    const float* __restrict__ wp, float* __restrict__ out)
{
    __shared__ __align__(16) v2f s_xk[4][8][2][16];   // 8 KB  [t][m][row][p]
    __shared__ float4 s_uk[4][16][16];                // 16 KB [t][j][p]
    __shared__ float4 s_uv[4][16][16];                // 16 KB

    const int tid = threadIdx.x;          // 0..255
    const int bid = blockIdx.x;           // ((bb*64+o)*16)+tq ; 4096 blocks
    const int tq  = bid & 15;             // tile quad: rows tq*4..tq*4+3
    const int o   = (bid >> 4) & 63;
    const int bb  = bid >> 10;
    const int r = o & 3, qch = o >> 2;

    const v2f*    __restrict__ x2 = (const v2f*)x;    // v2f strides: m 2048, row 32
    const float4* __restrict__ x4 = (const float4*)x; // f4 strides: m 1024, row 16

    // ---- A: issue stage-1 k/v staging loads (float4 = 2 v2f each) ----
    float4 s1v[2];
    #pragma unroll
    for (int it = 0; it < 2; it++) {
        const int idx = it * 256 + tid;   // 512 = 4t * 8m * 2row * 8f
        const int f = idx & 7, row = (idx >> 3) & 1, m = (idx >> 4) & 7, t = idx >> 7;
        const int y0 = tq * 4 + (t >> 1) * 2, w4 = (t & 1) * 8;
        s1v[it] = x4[((bb * 16 + qch) * 8 + m) * 1024 + (y0 + row) * 16 + w4 + f];
    }

    // ---- C: q loads + q-conv + residual for 4 i (hides A latency) ----
    const int p3 = tid & 15, ig4 = (tid >> 4) & 3, t3 = tid >> 6;
    const int y03 = tq * 4 + (t3 >> 1) * 2, ww03 = (t3 & 1) * 16;
    const int sp = y03 * 32 + ww03 + p3;  // v2f offset within a 64x64 plane

    float wqr[8];
    #pragma unroll
    for (int m = 0; m < 8; m++)
        wqr[m] = QSCALE * wq[(o << 3) + m];          // uniform scalar loads

    v2f uqa[4], uqb[4], rsa[4], rsb[4];
    #pragma unroll
    for (int ii = 0; ii < 4; ii++) {
        const int i = ig4 * 4 + ii;
        const int bq = (bb * 16 + i) * 16384 + sp;
        v2f qa[8], qb[8];
        #pragma unroll
        for (int m = 0; m < 8; m++) {                // lanes 0-15 coalesced 128B
            qa[m] = x2[bq + m * 2048];
            qb[m] = x2[bq + m * 2048 + 32];
        }
        v2f ua = {0.f,0.f}, ub = {0.f,0.f}, ra = {0.f,0.f}, rb = {0.f,0.f};
        #pragma unroll
        for (int m = 0; m < 8; m++) {
            ua += qa[m] * wqr[m];  ub += qb[m] * wqr[m];
            ra += qa[m];           rb += qb[m];
        }
        uqa[ii] = ua; uqb[ii] = ub; rsa[ii] = ra; rsb[ii] = rb;
    }

    // ---- B: stage-2 weight loads from GLOBAL (2 KB total, L1-resident;
    //         issued late so latency hides under s_xk wait + barrier) ----
    const int p2 = tid & 15, jg = (tid >> 4) & 7, th = tid >> 7;
    const int j0 = jg * 2, j1 = j0 + 1;
    float wk0[8], wk1[8], wv0[8], wv1[8];
    {
        const float4* wk4 = (const float4*)wk;
        const float4* wv4 = (const float4*)wv;
        const int rb0 = (r * 16 + j0) * 2, rb1 = (r * 16 + j1) * 2;
        *(float4*)&wk0[0] = wk4[rb0];     *(float4*)&wk0[4] = wk4[rb0 + 1];
        *(float4*)&wk1[0] = wk4[rb1];     *(float4*)&wk1[4] = wk4[rb1 + 1];
        *(float4*)&wv0[0] = wv4[rb0];     *(float4*)&wv0[4] = wv4[rb0 + 1];
        *(float4*)&wv1[0] = wv4[rb1];     *(float4*)&wv1[4] = wv4[rb1 + 1];
    }
    const float wp0 = wp[0], wp1 = wp[1];

    // ---- D: s_xk stores (A is oldest outstanding vmem -> short wait) ----
    #pragma unroll
    for (int it = 0; it < 2; it++) {
        const int idx = it * 256 + tid;
        const int f = idx & 7, row = (idx >> 3) & 1, m = (idx >> 4) & 7, t = idx >> 7;
        *(float4*)&s_xk[t][m][row][f * 2] = s1v[it];
    }
    __syncthreads();

    // ---- stage 2: uk/uv conv, thread = (p2, j0/j1, 2 tiles) ----
    const float step = 2.0f / 63.0f;
    #pragma unroll
    for (int tt2 = 0; tt2 < 2; tt2++) {
        const int t = th * 2 + tt2;
        const int y0 = tq * 4 + (t >> 1) * 2, ww0 = (t & 1) * 16;
        const int wwp = ww0 + p2;
        const float lx0 = -1.0f + step * (float)(wwp << 1);
        const float lx1 = lx0 + step;
        const float ly0 = -1.0f + step * (float)y0;
        const float ly1 = ly0 + step;
        const v2f pea = { 2.0f*(wp0*lx0 + wp1*ly0), 2.0f*(wp0*lx1 + wp1*ly0) };
        const v2f peb = { 2.0f*(wp0*lx0 + wp1*ly1), 2.0f*(wp0*lx1 + wp1*ly1) };
        v2f k0a = pea, k0b = peb, k1a = pea, k1b = peb;
        v2f v0a = {0.f,0.f}, v0b = {0.f,0.f}, v1a = {0.f,0.f}, v1b = {0.f,0.f};
        #pragma unroll
        for (int m = 0; m < 8; m++) {
            const v2f xa = s_xk[t][m][0][p2];   // one read set feeds 2 j
            const v2f xb = s_xk[t][m][1][p2];
            k0a += xa * wk0[m];  k0b += xb * wk0[m];
            k1a += xa * wk1[m];  k1b += xb * wk1[m];
            v0a += xa * wv0[m];  v0b += xb * wv0[m];
            v1a += xa * wv1[m];  v1b += xb * wv1[m];
        }
        s_uk[t][j0][p2] = make_float4(k0a.x, k0a.y, k0b.x, k0b.y);
        s_uk[t][j1][p2] = make_float4(k1a.x, k1a.y, k1b.x, k1b.y);
        s_uv[t][j0][p2] = make_float4(v0a.x, v0a.y, v0b.x, v0b.y);
        s_uv[t][j1][p2] = make_float4(v1a.x, v1a.y, v1b.x, v1b.y);
    }
    __syncthreads();

    // ---- stage 3: fused att + softmax + AV, 4 i per thread ----
    v2f oa[4], ob[4]; float sum[4];
    #pragma unroll
    for (int ii = 0; ii < 4; ii++) {
        oa[ii] = (v2f){0.f,0.f}; ob[ii] = (v2f){0.f,0.f}; sum[ii] = 0.f;
    }

    #pragma unroll
    for (int j = 0; j < 16; j++) {
        const float4 k4 = s_uk[t3][j][p3];    // 4-lane broadcast: free
        const float4 v4 = s_uv[t3][j][p3];
        const v2f ka = {k4.x, k4.y}, kb = {k4.z, k4.w};
        const v2f va = {v4.x, v4.y}, vb = {v4.z, v4.w};
        #pragma unroll
        for (int ii = 0; ii < 4; ii++) {
            v2f t0 = uqa[ii] * ka;
            t0 += uqb[ii] * kb;
            const float e = EXP_FN(t0.x + t0.y);
            sum[ii] += e;
            oa[ii] += va * e;
            ob[ii] += vb * e;
        }
    }

    v2f* __restrict__ out2 = (v2f*)out;
    #pragma unroll
    for (int ii = 0; ii < 4; ii++) {
        const int i = ig4 * 4 + ii;
        const float rcp = 1.0f / sum[ii];
        const v2f outa = oa[ii] * rcp + rsa[ii] * 0.125f;   // residual = mean/m
        const v2f outb = ob[ii] * rcp + rsb[ii] * 0.125f;
        const int obi = ((bb * 16 + i) * 64 + o) * 2048 + sp;
        out2[obi]      = outa;    // row y03
        out2[obi + 32] = outb;    // row y03+1
    }
}

extern "C" void kernel_launch(void* const* d_in, const int* in_sizes, int n_in,
                              void* d_out, int out_size, void* d_ws, size_t ws_size,
                              hipStream_t stream) {
    const float* x  = (const float*)d_in[0];
    const float* wq = (const float*)d_in[1];
    const float* wk = (const float*)d_in[2];
    const float* wv = (const float*)d_in[3];
    const float* wp = (const float*)d_in[4];
    float* out = (float*)d_out;
    // 4 bb * 64 o * 16 tile-quads = 4096 blocks of 256 threads
    adapt_attn<<<dim3(4096), dim3(256), 0, stream>>>(x, wq, wk, wv, wp, out);
}